// Round 5
// baseline (997.779 us; speedup 1.0000x reference)
//
#include <hip/hip_runtime.h>
#include <hip/hip_cooperative_groups.h>

namespace cg = cooperative_groups;

#define NBq 16384
#define NXq 512
#define NUq 256
#define NYq 128
#define NQq 256
#define KP  1024   // P width: [x(512) | w(256) | u(256)]
#define AUGW 1536  // [E(512) | F(512) | B1(256) | B2(256)]

typedef __attribute__((ext_vector_type(8))) short short8;
typedef __attribute__((ext_vector_type(4))) float f32x4;

__device__ __forceinline__ ushort f2bf(float f) {
  uint x = __float_as_uint(f);
  x += 0x7FFFu + ((x >> 16) & 1u);   // RNE
  return (ushort)(x >> 16);
}

// async global->LDS, 16B per lane; lptr must be wave-uniform (lane i lands at lptr + i*16B)
__device__ __forceinline__ void load_lds16(const ushort* g, ushort* l) {
  __builtin_amdgcn_global_load_lds(
      (const __attribute__((address_space(1))) unsigned int*)g,
      (__attribute__((address_space(3))) unsigned int*)(uintptr_t)l,
      16, 0, 0);
}

// ---------------- fused prep: pack x,u -> P ; AUG ; Wxu ; D11B ; Wfull static rows ----------------
__global__ __launch_bounds__(256) void k_prep(const float* __restrict__ x, const float* __restrict__ u,
                                              const float* __restrict__ E, const float* __restrict__ F,
                                              const float* __restrict__ B1, const float* __restrict__ B2,
                                              const float* __restrict__ C1, const float* __restrict__ C2,
                                              const float* __restrict__ D11, const float* __restrict__ D12,
                                              const float* __restrict__ D21,
                                              ushort* __restrict__ P, float* __restrict__ AUG,
                                              ushort* __restrict__ Wxu, ushort* __restrict__ D11B,
                                              ushort* __restrict__ Wfull) {
  int b = blockIdx.x, tid = threadIdx.x;
  if (b < 12288) {                       // pack x,u (float4 -> bf16x4)
    int idx = b * 256 + tid;
    const int nx4 = NBq * NXq / 4;
    if (idx < nx4) {
      float4 v = *(const float4*)(x + (size_t)idx * 4);
      int row = idx >> 7, c4 = idx & 127;
      ushort4 h = { f2bf(v.x), f2bf(v.y), f2bf(v.z), f2bf(v.w) };
      *(ushort4*)(P + (size_t)row * KP + c4 * 4) = h;
    } else {
      int i = idx - nx4;
      float4 v = *(const float4*)(u + (size_t)i * 4);
      int row = i >> 6, c4 = i & 63;
      ushort4 h = { f2bf(v.x), f2bf(v.y), f2bf(v.z), f2bf(v.w) };
      *(ushort4*)(P + (size_t)row * KP + 768 + c4 * 4) = h;
    }
  } else if (b < 15360) {                // AUG = [E | F B1 B2]
    int idx = (b - 12288) * 256 + tid;
    int r = idx / AUGW, c = idx % AUGW;
    float v;
    if (c < 512)       v = E[r * 512 + c];
    else if (c < 1024) v = F[r * 512 + (c - 512)];
    else if (c < 1280) v = B1[r * 256 + (c - 1024)];
    else               v = B2[r * 256 + (c - 1280)];
    AUG[idx] = v;
  } else if (b < 16384) {                // Wxu = [C1 | 0 | D12] bf16
    int idx = (b - 15360) * 256 + tid;
    int r = idx >> 10, k = idx & 1023;
    float v;
    if (k < 512)      v = C1[r * 512 + k];
    else if (k < 768) v = 0.f;
    else              v = D12[r * 256 + (k - 768)];
    Wxu[idx] = f2bf(v);
  } else if (b < 16640) {                // D11 -> bf16
    int idx = (b - 16384) * 256 + tid;
    D11B[idx] = f2bf(D11[idx]);
  } else {                               // Wfull rows 512..639 = [C2 | D21 | 0]
    int idx = (b - 16640) * 256 + tid;   // < 131072
    int j = idx >> 10, k = idx & 1023;
    float v;
    if (k < 512)      v = C2[j * 512 + k];
    else if (k < 768) v = D21[j * 256 + (k - 512)];
    else              v = 0.f;
    Wfull[(size_t)(512 + j) * KP + k] = f2bf(v);
  }
}

// ---------------- blocked Gauss-Jordan step body (shared by all 8 steps) ----------------
__device__ __forceinline__ void gj_step(const float* __restrict__ Ain, float* __restrict__ Aout,
                                        ushort* __restrict__ Wfull, int s, bool last, bool pivrow,
                                        int r0, int c0, int tid,
                                        float (&M)[64][132], float (&sP)[64][68],
                                        float (&sMC)[64][68], float (&pinv)[16][17]) {
  const int wave = tid >> 6, lane = tid & 63;
  const int s64 = s * 64;
  const int r2 = tid >> 2, cq = (tid & 3) * 16;

  // ---- stage tiles (float4 coalesced) ----
  float av[16];
  #pragma unroll
  for (int c4 = 0; c4 < 4; ++c4) {
    float4 v = *(const float4*)(Ain + (size_t)(r0 + r2) * AUGW + c0 + cq + c4 * 4);
    av[c4 * 4 + 0] = v.x; av[c4 * 4 + 1] = v.y; av[c4 * 4 + 2] = v.z; av[c4 * 4 + 3] = v.w;
    *(float4*)(&sP[r2][cq + c4 * 4]) =
        *(const float4*)(Ain + (size_t)(s64 + r2) * AUGW + c0 + cq + c4 * 4);
    *(float4*)(&sMC[r2][cq + c4 * 4]) =
        *(const float4*)(Ain + (size_t)(r0 + r2) * AUGW + s64 + cq + c4 * 4);
    *(float4*)(&M[r2][cq + c4 * 4]) =
        *(const float4*)(Ain + (size_t)(s64 + r2) * AUGW + s64 + cq + c4 * 4);
  }
  #pragma unroll
  for (int c = 0; c < 16; ++c)
    M[r2][64 + cq + c] = (r2 == cq + c) ? 1.f : 0.f;
  __syncthreads();

  // ---- invert M (64x64) in place: 4 stages of 16-panel GJ ----
  for (int t = 0; t < 4; ++t) {
    const int kt = t * 16;
    if (wave == 0) {                      // 16x16 pivot inverse in registers via shfl
      const int cc = lane & 31;
      float q[16];
      #pragma unroll
      for (int r = 0; r < 16; ++r)
        q[r] = (cc < 16) ? M[kt + r][kt + cc] : ((r == cc - 16) ? 1.f : 0.f);
      #pragma unroll
      for (int p = 0; p < 16; ++p) {
        float piv = __shfl(q[p], p);
        float rp = __builtin_amdgcn_rcpf(piv);
        rp = rp * (2.f - piv * rp);
        float a[16];
        #pragma unroll
        for (int r = 0; r < 16; ++r) a[r] = __shfl(q[r], p);
        q[p] *= rp;
        #pragma unroll
        for (int r = 0; r < 16; ++r)
          if (r != p) q[r] = fmaf(-a[r], q[p], q[r]);
      }
      if (lane >= 16 && lane < 32) {
        #pragma unroll
        for (int r = 0; r < 16; ++r) pinv[r][lane - 16] = q[r];
      }
    }
    __syncthreads();
    {                                     // R = pinv @ M[kt:kt+16][0:128]
      const int ri = tid >> 4, j0 = (tid & 15) * 8;
      float rr[8] = {};
      #pragma unroll
      for (int k = 0; k < 16; ++k) {
        float pv = pinv[ri][k];
        #pragma unroll
        for (int c = 0; c < 8; ++c) rr[c] = fmaf(pv, M[kt + k][j0 + c], rr[c]);
      }
      __syncthreads();
      #pragma unroll
      for (int c = 0; c < 8; c += 4)
        *(float4*)(&M[kt + ri][j0 + c]) = make_float4(rr[c], rr[c+1], rr[c+2], rr[c+3]);
    }
    __syncthreads();
    {                                     // rank-16 eliminate outside pivot band
      const int r = lane, ch = wave * 32;
      const bool act = (r >> 4) != t;
      float mult[16], o2[32];
      if (act) {
        #pragma unroll
        for (int k = 0; k < 16; ++k) mult[k] = M[r][kt + k];
        #pragma unroll
        for (int c = 0; c < 32; c += 4) {
          float4 v = *(const float4*)(&M[r][ch + c]);
          o2[c] = v.x; o2[c+1] = v.y; o2[c+2] = v.z; o2[c+3] = v.w;
        }
      }
      __syncthreads();
      if (act) {
        #pragma unroll
        for (int k = 0; k < 16; ++k) {
          float mk = mult[k];
          #pragma unroll
          for (int c = 0; c < 32; ++c) o2[c] = fmaf(-mk, M[kt + k][ch + c], o2[c]);
        }
        #pragma unroll
        for (int c = 0; c < 32; c += 4)
          *(float4*)(&M[r][ch + c]) = make_float4(o2[c], o2[c+1], o2[c+2], o2[c+3]);
      }
    }
    __syncthreads();
  }

  // ---- PB = Dinv @ sP ----
  float pb[16] = {};
  #pragma unroll 4
  for (int q = 0; q < 64; ++q) {
    float dv = M[r2][64 + q];
    #pragma unroll
    for (int c = 0; c < 16; ++c) pb[c] = fmaf(dv, sP[q][cq + c], pb[c]);
  }
  __syncthreads();
  #pragma unroll
  for (int c = 0; c < 16; c += 4)
    *(float4*)(&sP[r2][cq + c]) = make_float4(pb[c], pb[c+1], pb[c+2], pb[c+3]);
  __syncthreads();

  // ---- out = av - MC @ PB (pivot r-tile: out = PB) ----
  float o[16];
  if (pivrow) {
    #pragma unroll
    for (int c = 0; c < 16; ++c) o[c] = pb[c];
  } else {
    #pragma unroll
    for (int c = 0; c < 16; ++c) o[c] = av[c];
    #pragma unroll 4
    for (int q = 0; q < 64; ++q) {
      float mc = sMC[r2][q];
      #pragma unroll
      for (int c = 0; c < 16; ++c) o[c] = fmaf(-mc, sP[q][cq + c], o[c]);
    }
  }
  if (last) {                       // G rows of Wfull (c0 >= 512 at s=7)
    int k0 = c0 - 512 + cq;
    #pragma unroll
    for (int c = 0; c < 16; c += 4) {
      ushort4 h = { f2bf(o[c]), f2bf(o[c+1]), f2bf(o[c+2]), f2bf(o[c+3]) };
      *(ushort4*)(Wfull + (size_t)(r0 + r2) * KP + k0 + c) = h;
    }
  } else {
    #pragma unroll
    for (int c = 0; c < 16; c += 4)
      *(float4*)(Aout + (size_t)(r0 + r2) * AUGW + c0 + cq + c) =
          make_float4(o[c], o[c+1], o[c+2], o[c+3]);
  }
}

// ---------------- all 8 GJ steps in one cooperative kernel (grid-sync between steps) ----------------
__global__ __launch_bounds__(256) void k_gjall(float* __restrict__ A0, float* __restrict__ A1,
                                               ushort* __restrict__ Wfull) {
  __shared__ float M[64][132];
  __shared__ float sP[64][68];
  __shared__ float sMC[64][68];
  __shared__ float pinv[16][17];
  cg::grid_group grid = cg::this_grid();
  const int tid = threadIdx.x;
  for (int s = 0; s < 8; ++s) {
    if (s) {
      __threadfence();
      grid.sync();
    }
    const float* Ain = (s & 1) ? A1 : A0;
    float* Aout = (s & 1) ? A0 : A1;
    const int nc = 23 - s;
    if ((int)blockIdx.x < 8 * nc) {
      int rt = blockIdx.x & 7;
      int c0 = (s + 1 + (int)(blockIdx.x >> 3)) * 64;
      gj_step(Ain, Aout, Wfull, s, s == 7, rt == s, rt * 64, c0, tid, M, sP, sMC, pinv);
    }
  }
}

// ---------------- bf16 MFMA GEMM (m97-style global_load_lds staging) ----------------
// out[m][n] = sum_k P[m][k] * W[n][k]; BM=BN=128, BK=32, 4 waves (2x2 of 64x64)
template<bool SPLIT>
__global__ __launch_bounds__(256) void k_gemm(const ushort* __restrict__ P, const ushort* __restrict__ W,
                                              float* __restrict__ out) {
  __shared__ ushort sA[128 * 32];
  __shared__ ushort sB[128 * 32];
  int tid = threadIdx.x;
  int lane = tid & 63, wave = tid >> 6;
  int wm = wave & 1, wn = wave >> 1;
  int m0 = blockIdx.x * 128, n0 = blockIdx.y * 128;
  int r16 = lane & 15, kq = lane >> 4;
  // staging: wave stages rows [wave*32, wave*32+32) of A and B; lane -> (row=lane>>2, seg=lane&3)
  const ushort* gA0 = P + (size_t)(m0 + wave * 32 + (lane >> 2)) * KP + (lane & 3) * 8;
  const ushort* gB0 = W + (size_t)(n0 + wave * 32 + (lane >> 2)) * KP + (lane & 3) * 8;
  ushort* lA = sA + wave * 32 * 32;   // wave-uniform LDS bases
  ushort* lB = sB + wave * 32 * 32;
  f32x4 acc[4][4] = {};
  for (int kb = 0; kb < KP / 32; ++kb) {
    int off = kb * 32;
    load_lds16(gA0 + off, lA);
    load_lds16(gA0 + off + (size_t)16 * KP, lA + 512);
    load_lds16(gB0 + off, lB);
    load_lds16(gB0 + off + (size_t)16 * KP, lB + 512);
    __syncthreads();
    short8 af[4], bf[4];
    #pragma unroll
    for (int t = 0; t < 4; ++t) {
      af[t] = *(const short8*)(&sA[(wm * 64 + t * 16 + r16) * 32 + kq * 8]);
      bf[t] = *(const short8*)(&sB[(wn * 64 + t * 16 + r16) * 32 + kq * 8]);
    }
    #pragma unroll
    for (int mt = 0; mt < 4; ++mt)
      #pragma unroll
      for (int nt = 0; nt < 4; ++nt)
        acc[mt][nt] = __builtin_amdgcn_mfma_f32_16x16x32_bf16(af[mt], bf[nt], acc[mt][nt], 0, 0, 0);
    __syncthreads();
  }
  #pragma unroll
  for (int mt = 0; mt < 4; ++mt)
    #pragma unroll
    for (int nt = 0; nt < 4; ++nt)
      #pragma unroll
      for (int i = 0; i < 4; ++i) {
        int m = m0 + wm * 64 + mt * 16 + kq * 4 + i;
        int n = n0 + wn * 64 + nt * 16 + r16;
        float val = acc[mt][nt][i];
        if (SPLIT) {
          if (n < NXq) out[(size_t)m * NXq + n] = val;
          else out[(size_t)NBq * NXq + (size_t)m * NYq + (n - NXq)] = val;
        } else {
          out[(size_t)m * NQq + n] = val;
        }
      }
}

// ---------------- MFMA-blocked tanh forward substitution (barrier-free main loop) ----------------
#define WSTRIDE 264

struct Pre {
  f32x4 xuv;
  short8 b[8];
  float rl, bvrl;
};

template<int t>
__device__ __forceinline__ void tile_loads(const float* __restrict__ xu,
                                           const ushort* __restrict__ D11B,
                                           const float* __restrict__ lam,
                                           const float* __restrict__ bv,
                                           int col, int quad, int r0w, Pre& pre) {
  constexpr int kt = t * 16;
  constexpr int cmax = (t + 1) >> 1;
  #pragma unroll
  for (int i = 0; i < 4; ++i)
    pre.xuv[i] = xu[(size_t)(r0w + quad * 4 + i) * NQq + kt + col];
  #pragma unroll
  for (int c = 0; c < cmax; ++c)
    pre.b[c] = *(const short8*)(D11B + (size_t)(kt + col) * NQq + c * 32 + quad * 8);
  float l = lam[kt + col];
  pre.rl = 1.0f / l;
  pre.bvrl = bv[kt + col] * pre.rl;
}

template<int t>
__device__ __forceinline__ void do_tile(const float* __restrict__ xu,
                                        const ushort* __restrict__ D11B,
                                        const float* __restrict__ lam,
                                        const float* __restrict__ bv,
                                        ushort* wb, const float (*d11diag)[16][17],
                                        short8 (&whiF)[8], int lane, int col, int quad,
                                        int r0w, Pre& cur, Pre& nxt) {
  constexpr int kt = t * 16;
  constexpr int cmax = (t + 1) >> 1;
  if constexpr (t < 15)
    tile_loads<t + 1>(xu, D11B, lam, bv, col, quad, r0w, nxt);
  f32x4 acc = cur.xuv;
  #pragma unroll
  for (int c = 0; c < cmax; ++c)
    acc = __builtin_amdgcn_mfma_f32_16x16x32_bf16(whiF[c], cur.b[c], acc, 0, 0, 0);
  const float rl = cur.rl, bvrl = cur.bvrl;
  float w0r = 0.f, w1r = 0.f, w2r = 0.f, w3r = 0.f;
  #pragma unroll
  for (int n = 0; n < 16; ++n) {
    float dv = d11diag[t][col][n];
    float v0 = fmaf(acc[0], rl, bvrl);
    float v1 = fmaf(acc[1], rl, bvrl);
    float v2 = fmaf(acc[2], rl, bvrl);
    float v3 = fmaf(acc[3], rl, bvrl);
    float w0 = fmaf(-2.f, __builtin_amdgcn_rcpf(1.f + __expf(2.f * v0)), 1.f);
    float w1 = fmaf(-2.f, __builtin_amdgcn_rcpf(1.f + __expf(2.f * v1)), 1.f);
    float w2 = fmaf(-2.f, __builtin_amdgcn_rcpf(1.f + __expf(2.f * v2)), 1.f);
    float w3 = fmaf(-2.f, __builtin_amdgcn_rcpf(1.f + __expf(2.f * v3)), 1.f);
    bool wr = (col == n);
    w0r = wr ? w0 : w0r;
    w1r = wr ? w1 : w1r;
    w2r = wr ? w2 : w2r;
    w3r = wr ? w3 : w3r;
    int src = (lane & 48) | n;
    float b0 = __shfl(w0, src);
    float b1 = __shfl(w1, src);
    float b2 = __shfl(w2, src);
    float b3 = __shfl(w3, src);
    if (col > n) {
      acc[0] = fmaf(b0, dv, acc[0]);
      acc[1] = fmaf(b1, dv, acc[1]);
      acc[2] = fmaf(b2, dv, acc[2]);
      acc[3] = fmaf(b3, dv, acc[3]);
    }
  }
  wb[(quad * 4 + 0) * WSTRIDE + kt + col] = f2bf(w0r);
  wb[(quad * 4 + 1) * WSTRIDE + kt + col] = f2bf(w1r);
  wb[(quad * 4 + 2) * WSTRIDE + kt + col] = f2bf(w2r);
  wb[(quad * 4 + 3) * WSTRIDE + kt + col] = f2bf(w3r);
  if ((quad >> 1) == (t & 1)) {
    constexpr int c = t >> 1;
    whiF[c] = *(const short8*)(wb + (lane & 15) * WSTRIDE + c * 32 + quad * 8);
  }
}

__global__ __launch_bounds__(256) void k_solve(const float* __restrict__ xu,
                                               const float* __restrict__ D11,
                                               const ushort* __restrict__ D11B,
                                               const float* __restrict__ lam,
                                               const float* __restrict__ bv,
                                               ushort* __restrict__ P) {
  __shared__ ushort wB[4][16 * WSTRIDE];   // per-wave bf16 w
  __shared__ float d11diag[16][16][17];    // all 16 diagonal D11 blocks
  const int tid = threadIdx.x;
  const int wave = tid >> 6, lane = tid & 63;
  const int col = lane & 15, quad = lane >> 4;
  const int r0w = blockIdx.x * 64 + wave * 16;
  for (int i = tid; i < 4096; i += 256) {
    int tt = i >> 8, r = (i >> 4) & 15, c = i & 15;
    d11diag[tt][r][c] = D11[(size_t)(tt * 16 + r) * NQq + tt * 16 + c];
  }
  Pre pre0, pre1;
  tile_loads<0>(xu, D11B, lam, bv, col, quad, r0w, pre0);
  __syncthreads();                          // the only block-wide barrier
  ushort* wb = &wB[wave][0];
  short8 whiF[8] = {};
  do_tile<0>(xu, D11B, lam, bv, wb, d11diag, whiF, lane, col, quad, r0w, pre0, pre1);
  do_tile<1>(xu, D11B, lam, bv, wb, d11diag, whiF, lane, col, quad, r0w, pre1, pre0);
  do_tile<2>(xu, D11B, lam, bv, wb, d11diag, whiF, lane, col, quad, r0w, pre0, pre1);
  do_tile<3>(xu, D11B, lam, bv, wb, d11diag, whiF, lane, col, quad, r0w, pre1, pre0);
  do_tile<4>(xu, D11B, lam, bv, wb, d11diag, whiF, lane, col, quad, r0w, pre0, pre1);
  do_tile<5>(xu, D11B, lam, bv, wb, d11diag, whiF, lane, col, quad, r0w, pre1, pre0);
  do_tile<6>(xu, D11B, lam, bv, wb, d11diag, whiF, lane, col, quad, r0w, pre0, pre1);
  do_tile<7>(xu, D11B, lam, bv, wb, d11diag, whiF, lane, col, quad, r0w, pre1, pre0);
  do_tile<8>(xu, D11B, lam, bv, wb, d11diag, whiF, lane, col, quad, r0w, pre0, pre1);
  do_tile<9>(xu, D11B, lam, bv, wb, d11diag, whiF, lane, col, quad, r0w, pre1, pre0);
  do_tile<10>(xu, D11B, lam, bv, wb, d11diag, whiF, lane, col, quad, r0w, pre0, pre1);
  do_tile<11>(xu, D11B, lam, bv, wb, d11diag, whiF, lane, col, quad, r0w, pre1, pre0);
  do_tile<12>(xu, D11B, lam, bv, wb, d11diag, whiF, lane, col, quad, r0w, pre0, pre1);
  do_tile<13>(xu, D11B, lam, bv, wb, d11diag, whiF, lane, col, quad, r0w, pre1, pre0);
  do_tile<14>(xu, D11B, lam, bv, wb, d11diag, whiF, lane, col, quad, r0w, pre0, pre1);
  do_tile<15>(xu, D11B, lam, bv, wb, d11diag, whiF, lane, col, quad, r0w, pre1, pre0);
  #pragma unroll
  for (int it = 0; it < 8; ++it) {
    int f = it * 64 + lane;
    int m = f >> 5, k8 = f & 31;
    uint4 v = *(const uint4*)(wb + m * WSTRIDE + k8 * 8);
    *(uint4*)(P + (size_t)(r0w + m) * KP + NXq + k8 * 8) = v;
  }
}

extern "C" void kernel_launch(void* const* d_in, const int* in_sizes, int n_in,
                              void* d_out, int out_size, void* d_ws, size_t ws_size,
                              hipStream_t stream) {
  const float* x   = (const float*)d_in[0];
  const float* u   = (const float*)d_in[1];
  const float* F   = (const float*)d_in[2];
  const float* B1  = (const float*)d_in[3];
  const float* B2  = (const float*)d_in[4];
  const float* C1  = (const float*)d_in[5];
  const float* C2  = (const float*)d_in[6];
  const float* D11 = (const float*)d_in[7];
  const float* D12 = (const float*)d_in[8];
  const float* D21 = (const float*)d_in[9];
  const float* E   = (const float*)d_in[10];
  const float* lam = (const float*)d_in[11];
  const float* bv  = (const float*)d_in[12];

  char* ws = (char*)d_ws;
  ushort* P    = (ushort*)ws;                                     // 32 MB
  float* xu    = (float*)(ws + (size_t)(32u << 20));              // 16 MB
  float* AUG0  = (float*)(ws + (size_t)(48u << 20));              // 3 MB
  float* AUG1  = (float*)(ws + (size_t)(52u << 20));              // 3 MB
  ushort* Wfull = (ushort*)(ws + (size_t)(56u << 20));            // 1.25 MB bf16
  ushort* Wxu   = (ushort*)(ws + (size_t)(58u << 20));            // 0.5 MB bf16
  ushort* D11B  = (ushort*)(ws + (size_t)(59u << 20));            // 128 KB bf16
  float* out   = (float*)d_out;

  k_prep<<<17152, 256, 0, stream>>>(x, u, E, F, B1, B2, C1, C2, D11, D12, D21,
                                    P, AUG0, Wxu, D11B, Wfull);
  void* gjArgs[] = { (void*)&AUG0, (void*)&AUG1, (void*)&Wfull };
  hipLaunchCooperativeKernel((void*)k_gjall, dim3(184), dim3(256), gjArgs, 0, stream);
  k_gemm<false><<<dim3(128, 2), 256, 0, stream>>>(P, Wxu, xu);    // xu = x@C1^T + u@D12^T
  k_solve<<<256, 256, 0, stream>>>(xu, D11, D11B, lam, bv, P);    // w -> P[:,512:768]
  k_gemm<true><<<dim3(128, 5), 256, 0, stream>>>(P, Wfull, out);  // dx, y
}

// Round 6
// 486.506 us; speedup vs baseline: 2.0509x; 2.0509x over previous
//
#include <hip/hip_runtime.h>

#define NBq 16384
#define NXq 512
#define NUq 256
#define NYq 128
#define NQq 256
#define KP  1024   // P width: [x(512) | w(256) | u(256)]
#define AUGW 1536  // [E(512) | F(512) | B1(256) | B2(256)]

typedef __attribute__((ext_vector_type(8))) short short8;
typedef __attribute__((ext_vector_type(4))) float f32x4;

__device__ __forceinline__ ushort f2bf(float f) {
  uint x = __float_as_uint(f);
  x += 0x7FFFu + ((x >> 16) & 1u);   // RNE
  return (ushort)(x >> 16);
}

// async global->LDS, 16B per lane; lds base wave-uniform (lane i lands at base + i*16B)
__device__ __forceinline__ void load_lds16(const ushort* g, ushort* l) {
  __builtin_amdgcn_global_load_lds(
      (const __attribute__((address_space(1))) unsigned int*)g,
      (__attribute__((address_space(3))) unsigned int*)(uintptr_t)l,
      16, 0, 0);
}

// ---------------- fused prep: pack x,u -> P ; AUG ; Wxu ; D11B ; Wfull static rows ----------------
__global__ __launch_bounds__(256) void k_prep(const float* __restrict__ x, const float* __restrict__ u,
                                              const float* __restrict__ E, const float* __restrict__ F,
                                              const float* __restrict__ B1, const float* __restrict__ B2,
                                              const float* __restrict__ C1, const float* __restrict__ C2,
                                              const float* __restrict__ D11, const float* __restrict__ D12,
                                              const float* __restrict__ D21,
                                              ushort* __restrict__ P, float* __restrict__ AUG,
                                              ushort* __restrict__ Wxu, ushort* __restrict__ D11B,
                                              ushort* __restrict__ Wfull) {
  int b = blockIdx.x, tid = threadIdx.x;
  if (b < 12288) {                       // pack x,u (float4 -> bf16x4)
    int idx = b * 256 + tid;
    const int nx4 = NBq * NXq / 4;
    if (idx < nx4) {
      float4 v = *(const float4*)(x + (size_t)idx * 4);
      int row = idx >> 7, c4 = idx & 127;
      ushort4 h = { f2bf(v.x), f2bf(v.y), f2bf(v.z), f2bf(v.w) };
      *(ushort4*)(P + (size_t)row * KP + c4 * 4) = h;
    } else {
      int i = idx - nx4;
      float4 v = *(const float4*)(u + (size_t)i * 4);
      int row = i >> 6, c4 = i & 63;
      ushort4 h = { f2bf(v.x), f2bf(v.y), f2bf(v.z), f2bf(v.w) };
      *(ushort4*)(P + (size_t)row * KP + 768 + c4 * 4) = h;
    }
  } else if (b < 15360) {                // AUG = [E | F B1 B2]
    int idx = (b - 12288) * 256 + tid;
    int r = idx / AUGW, c = idx % AUGW;
    float v;
    if (c < 512)       v = E[r * 512 + c];
    else if (c < 1024) v = F[r * 512 + (c - 512)];
    else if (c < 1280) v = B1[r * 256 + (c - 1024)];
    else               v = B2[r * 256 + (c - 1280)];
    AUG[idx] = v;
  } else if (b < 16384) {                // Wxu = [C1 | 0 | D12] bf16
    int idx = (b - 15360) * 256 + tid;
    int r = idx >> 10, k = idx & 1023;
    float v;
    if (k < 512)      v = C1[r * 512 + k];
    else if (k < 768) v = 0.f;
    else              v = D12[r * 256 + (k - 768)];
    Wxu[idx] = f2bf(v);
  } else if (b < 16640) {                // D11 -> bf16
    int idx = (b - 16384) * 256 + tid;
    D11B[idx] = f2bf(D11[idx]);
  } else {                               // Wfull rows 512..639 = [C2 | D21 | 0]
    int idx = (b - 16640) * 256 + tid;   // < 131072
    int j = idx >> 10, k = idx & 1023;
    float v;
    if (k < 512)      v = C2[j * 512 + k];
    else if (k < 768) v = D21[j * 256 + (k - 512)];
    else              v = 0.f;
    Wfull[(size_t)(512 + j) * KP + k] = f2bf(v);
  }
}

// ---------------- blocked Gauss-Jordan step (8 dispatches; AUG stays L2-warm) ----------------
// Per block: invert pivot 64x64 via 4 stages of 16-panel GJ (16x16 pivot in regs
// via shfl on wave 0, rank-16 elimination by all waves), then PB = Dinv@panel,
// out = A - MC@PB (pivot r-tile: out = PB). Last step emits Wfull bf16 directly.
__global__ __launch_bounds__(256) void k_gj(const float* __restrict__ Ain, float* __restrict__ Aout,
                                            ushort* __restrict__ Wfull, int s, int last) {
  __shared__ float M[64][132];
  __shared__ float sP[64][68];
  __shared__ float sMC[64][68];
  __shared__ float pinv[16][17];
  const int tid = threadIdx.x;
  const int wave = tid >> 6, lane = tid & 63;
  const int s64 = s * 64, r0 = blockIdx.x * 64, c0 = (s + 1 + blockIdx.y) * 64;
  const int r2 = tid >> 2, cq = (tid & 3) * 16;

  // ---- stage tiles (float4 coalesced) ----
  float av[16];
  #pragma unroll
  for (int c4 = 0; c4 < 4; ++c4) {
    float4 v = *(const float4*)(Ain + (size_t)(r0 + r2) * AUGW + c0 + cq + c4 * 4);
    av[c4 * 4 + 0] = v.x; av[c4 * 4 + 1] = v.y; av[c4 * 4 + 2] = v.z; av[c4 * 4 + 3] = v.w;
    *(float4*)(&sP[r2][cq + c4 * 4]) =
        *(const float4*)(Ain + (size_t)(s64 + r2) * AUGW + c0 + cq + c4 * 4);
    *(float4*)(&sMC[r2][cq + c4 * 4]) =
        *(const float4*)(Ain + (size_t)(r0 + r2) * AUGW + s64 + cq + c4 * 4);
    *(float4*)(&M[r2][cq + c4 * 4]) =
        *(const float4*)(Ain + (size_t)(s64 + r2) * AUGW + s64 + cq + c4 * 4);
  }
  #pragma unroll
  for (int c = 0; c < 16; ++c)
    M[r2][64 + cq + c] = (r2 == cq + c) ? 1.f : 0.f;
  __syncthreads();

  // ---- invert M (64x64) in place: 4 stages of 16-panel GJ ----
  for (int t = 0; t < 4; ++t) {
    const int kt = t * 16;
    if (wave == 0) {                      // 16x16 pivot inverse in registers via shfl
      const int cc = lane & 31;
      float q[16];
      #pragma unroll
      for (int r = 0; r < 16; ++r)
        q[r] = (cc < 16) ? M[kt + r][kt + cc] : ((r == cc - 16) ? 1.f : 0.f);
      #pragma unroll
      for (int p = 0; p < 16; ++p) {
        float piv = __shfl(q[p], p);
        float rp = __builtin_amdgcn_rcpf(piv);
        rp = rp * (2.f - piv * rp);       // NR: fp32-exact reciprocal
        float a[16];
        #pragma unroll
        for (int r = 0; r < 16; ++r) a[r] = __shfl(q[r], p);
        q[p] *= rp;
        #pragma unroll
        for (int r = 0; r < 16; ++r)
          if (r != p) q[r] = fmaf(-a[r], q[p], q[r]);
      }
      if (lane >= 16 && lane < 32) {
        #pragma unroll
        for (int r = 0; r < 16; ++r) pinv[r][lane - 16] = q[r];
      }
    }
    __syncthreads();
    {                                     // R = pinv @ M[kt:kt+16][0:128]
      const int ri = tid >> 4, j0 = (tid & 15) * 8;
      float rr[8] = {};
      #pragma unroll
      for (int k = 0; k < 16; ++k) {
        float pv = pinv[ri][k];
        #pragma unroll
        for (int c = 0; c < 8; ++c) rr[c] = fmaf(pv, M[kt + k][j0 + c], rr[c]);
      }
      __syncthreads();
      #pragma unroll
      for (int c = 0; c < 8; c += 4)
        *(float4*)(&M[kt + ri][j0 + c]) = make_float4(rr[c], rr[c+1], rr[c+2], rr[c+3]);
    }
    __syncthreads();
    {                                     // rank-16 eliminate outside pivot band
      const int r = lane, ch = wave * 32;
      const bool act = (r >> 4) != t;
      float mult[16], o2[32];
      if (act) {
        #pragma unroll
        for (int k = 0; k < 16; ++k) mult[k] = M[r][kt + k];
        #pragma unroll
        for (int c = 0; c < 32; c += 4) {
          float4 v = *(const float4*)(&M[r][ch + c]);
          o2[c] = v.x; o2[c+1] = v.y; o2[c+2] = v.z; o2[c+3] = v.w;
        }
      }
      __syncthreads();
      if (act) {
        #pragma unroll
        for (int k = 0; k < 16; ++k) {
          float mk = mult[k];
          #pragma unroll
          for (int c = 0; c < 32; ++c) o2[c] = fmaf(-mk, M[kt + k][ch + c], o2[c]);
        }
        #pragma unroll
        for (int c = 0; c < 32; c += 4)
          *(float4*)(&M[r][ch + c]) = make_float4(o2[c], o2[c+1], o2[c+2], o2[c+3]);
      }
    }
    __syncthreads();
  }

  // ---- PB = Dinv @ sP ----
  float pb[16] = {};
  #pragma unroll 4
  for (int q = 0; q < 64; ++q) {
    float dv = M[r2][64 + q];
    #pragma unroll
    for (int c = 0; c < 16; ++c) pb[c] = fmaf(dv, sP[q][cq + c], pb[c]);
  }
  __syncthreads();
  #pragma unroll
  for (int c = 0; c < 16; c += 4)
    *(float4*)(&sP[r2][cq + c]) = make_float4(pb[c], pb[c+1], pb[c+2], pb[c+3]);
  __syncthreads();

  // ---- out = av - MC @ PB (pivot r-tile: out = PB) ----
  float o[16];
  if (blockIdx.x == (unsigned)s) {
    #pragma unroll
    for (int c = 0; c < 16; ++c) o[c] = pb[c];
  } else {
    #pragma unroll
    for (int c = 0; c < 16; ++c) o[c] = av[c];
    #pragma unroll 4
    for (int q = 0; q < 64; ++q) {
      float mc = sMC[r2][q];
      #pragma unroll
      for (int c = 0; c < 16; ++c) o[c] = fmaf(-mc, sP[q][cq + c], o[c]);
    }
  }
  if (last) {                       // G rows of Wfull (c0 >= 512 at s=7)
    int k0 = c0 - 512 + cq;
    #pragma unroll
    for (int c = 0; c < 16; c += 4) {
      ushort4 h = { f2bf(o[c]), f2bf(o[c+1]), f2bf(o[c+2]), f2bf(o[c+3]) };
      *(ushort4*)(Wfull + (size_t)(r0 + r2) * KP + k0 + c) = h;
    }
  } else {
    #pragma unroll
    for (int c = 0; c < 16; c += 4)
      *(float4*)(Aout + (size_t)(r0 + r2) * AUGW + c0 + cq + c) =
          make_float4(o[c], o[c+1], o[c+2], o[c+3]);
  }
}

// ---------------- bf16 MFMA GEMM (m97-style global_load_lds staging) ----------------
// out[m][n] = sum_k P[m][k] * W[n][k]; BM=BN=128, BK=32, 4 waves (2x2 of 64x64)
template<bool SPLIT>
__global__ __launch_bounds__(256) void k_gemm(const ushort* __restrict__ P, const ushort* __restrict__ W,
                                              float* __restrict__ out) {
  __shared__ ushort sA[128 * 32];
  __shared__ ushort sB[128 * 32];
  int tid = threadIdx.x;
  int lane = tid & 63, wave = tid >> 6;
  int wm = wave & 1, wn = wave >> 1;
  int m0 = blockIdx.x * 128, n0 = blockIdx.y * 128;
  int r16 = lane & 15, kq = lane >> 4;
  // staging: wave stages rows [wave*32, wave*32+32); lane -> (row=lane>>2, seg=lane&3) = 16B*lane
  const ushort* gA0 = P + (size_t)(m0 + wave * 32 + (lane >> 2)) * KP + (lane & 3) * 8;
  const ushort* gB0 = W + (size_t)(n0 + wave * 32 + (lane >> 2)) * KP + (lane & 3) * 8;
  ushort* lA = sA + wave * 32 * 32;   // wave-uniform LDS bases
  ushort* lB = sB + wave * 32 * 32;
  f32x4 acc[4][4] = {};
  for (int kb = 0; kb < KP / 32; ++kb) {
    int off = kb * 32;
    load_lds16(gA0 + off, lA);
    load_lds16(gA0 + off + (size_t)16 * KP, lA + 512);
    load_lds16(gB0 + off, lB);
    load_lds16(gB0 + off + (size_t)16 * KP, lB + 512);
    __syncthreads();
    short8 af[4], bf[4];
    #pragma unroll
    for (int t = 0; t < 4; ++t) {
      af[t] = *(const short8*)(&sA[(wm * 64 + t * 16 + r16) * 32 + kq * 8]);
      bf[t] = *(const short8*)(&sB[(wn * 64 + t * 16 + r16) * 32 + kq * 8]);
    }
    #pragma unroll
    for (int mt = 0; mt < 4; ++mt)
      #pragma unroll
      for (int nt = 0; nt < 4; ++nt)
        acc[mt][nt] = __builtin_amdgcn_mfma_f32_16x16x32_bf16(af[mt], bf[nt], acc[mt][nt], 0, 0, 0);
    __syncthreads();
  }
  #pragma unroll
  for (int mt = 0; mt < 4; ++mt)
    #pragma unroll
    for (int nt = 0; nt < 4; ++nt)
      #pragma unroll
      for (int i = 0; i < 4; ++i) {
        int m = m0 + wm * 64 + mt * 16 + kq * 4 + i;
        int n = n0 + wn * 64 + nt * 16 + r16;
        float val = acc[mt][nt][i];
        if (SPLIT) {
          if (n < NXq) out[(size_t)m * NXq + n] = val;
          else out[(size_t)NBq * NXq + (size_t)m * NYq + (n - NXq)] = val;
        } else {
          out[(size_t)m * NQq + n] = val;
        }
      }
}

// ---------------- MFMA-blocked tanh forward substitution (barrier-free main loop) ----------------
#define WSTRIDE 264

struct Pre {
  f32x4 xuv;
  short8 b[8];
  float rl, bvrl;
};

template<int t>
__device__ __forceinline__ void tile_loads(const float* __restrict__ xu,
                                           const ushort* __restrict__ D11B,
                                           const float* __restrict__ lam,
                                           const float* __restrict__ bv,
                                           int col, int quad, int r0w, Pre& pre) {
  constexpr int kt = t * 16;
  constexpr int cmax = (t + 1) >> 1;
  #pragma unroll
  for (int i = 0; i < 4; ++i)
    pre.xuv[i] = xu[(size_t)(r0w + quad * 4 + i) * NQq + kt + col];
  #pragma unroll
  for (int c = 0; c < cmax; ++c)
    pre.b[c] = *(const short8*)(D11B + (size_t)(kt + col) * NQq + c * 32 + quad * 8);
  float l = lam[kt + col];
  pre.rl = 1.0f / l;
  pre.bvrl = bv[kt + col] * pre.rl;
}

template<int t>
__device__ __forceinline__ void do_tile(const float* __restrict__ xu,
                                        const ushort* __restrict__ D11B,
                                        const float* __restrict__ lam,
                                        const float* __restrict__ bv,
                                        ushort* wb, const float (*d11diag)[16][17],
                                        short8 (&whiF)[8], int lane, int col, int quad,
                                        int r0w, Pre& cur, Pre& nxt) {
  constexpr int kt = t * 16;
  constexpr int cmax = (t + 1) >> 1;
  if constexpr (t < 15)
    tile_loads<t + 1>(xu, D11B, lam, bv, col, quad, r0w, nxt);
  f32x4 acc = cur.xuv;
  #pragma unroll
  for (int c = 0; c < cmax; ++c)
    acc = __builtin_amdgcn_mfma_f32_16x16x32_bf16(whiF[c], cur.b[c], acc, 0, 0, 0);
  const float rl = cur.rl, bvrl = cur.bvrl;
  float w0r = 0.f, w1r = 0.f, w2r = 0.f, w3r = 0.f;
  #pragma unroll
  for (int n = 0; n < 16; ++n) {
    float dv = d11diag[t][col][n];
    float v0 = fmaf(acc[0], rl, bvrl);
    float v1 = fmaf(acc[1], rl, bvrl);
    float v2 = fmaf(acc[2], rl, bvrl);
    float v3 = fmaf(acc[3], rl, bvrl);
    float w0 = fmaf(-2.f, __builtin_amdgcn_rcpf(1.f + __expf(2.f * v0)), 1.f);
    float w1 = fmaf(-2.f, __builtin_amdgcn_rcpf(1.f + __expf(2.f * v1)), 1.f);
    float w2 = fmaf(-2.f, __builtin_amdgcn_rcpf(1.f + __expf(2.f * v2)), 1.f);
    float w3 = fmaf(-2.f, __builtin_amdgcn_rcpf(1.f + __expf(2.f * v3)), 1.f);
    bool wr = (col == n);
    w0r = wr ? w0 : w0r;
    w1r = wr ? w1 : w1r;
    w2r = wr ? w2 : w2r;
    w3r = wr ? w3 : w3r;
    int src = (lane & 48) | n;
    float b0 = __shfl(w0, src);
    float b1 = __shfl(w1, src);
    float b2 = __shfl(w2, src);
    float b3 = __shfl(w3, src);
    if (col > n) {
      acc[0] = fmaf(b0, dv, acc[0]);
      acc[1] = fmaf(b1, dv, acc[1]);
      acc[2] = fmaf(b2, dv, acc[2]);
      acc[3] = fmaf(b3, dv, acc[3]);
    }
  }
  wb[(quad * 4 + 0) * WSTRIDE + kt + col] = f2bf(w0r);
  wb[(quad * 4 + 1) * WSTRIDE + kt + col] = f2bf(w1r);
  wb[(quad * 4 + 2) * WSTRIDE + kt + col] = f2bf(w2r);
  wb[(quad * 4 + 3) * WSTRIDE + kt + col] = f2bf(w3r);
  if ((quad >> 1) == (t & 1)) {
    constexpr int c = t >> 1;
    whiF[c] = *(const short8*)(wb + (lane & 15) * WSTRIDE + c * 32 + quad * 8);
  }
}

__global__ __launch_bounds__(256) void k_solve(const float* __restrict__ xu,
                                               const float* __restrict__ D11,
                                               const ushort* __restrict__ D11B,
                                               const float* __restrict__ lam,
                                               const float* __restrict__ bv,
                                               ushort* __restrict__ P) {
  __shared__ ushort wB[4][16 * WSTRIDE];   // per-wave bf16 w
  __shared__ float d11diag[16][16][17];    // all 16 diagonal D11 blocks
  const int tid = threadIdx.x;
  const int wave = tid >> 6, lane = tid & 63;
  const int col = lane & 15, quad = lane >> 4;
  const int r0w = blockIdx.x * 64 + wave * 16;
  for (int i = tid; i < 4096; i += 256) {
    int tt = i >> 8, r = (i >> 4) & 15, c = i & 15;
    d11diag[tt][r][c] = D11[(size_t)(tt * 16 + r) * NQq + tt * 16 + c];
  }
  Pre pre0, pre1;
  tile_loads<0>(xu, D11B, lam, bv, col, quad, r0w, pre0);
  __syncthreads();                          // the only block-wide barrier
  ushort* wb = &wB[wave][0];
  short8 whiF[8] = {};
  do_tile<0>(xu, D11B, lam, bv, wb, d11diag, whiF, lane, col, quad, r0w, pre0, pre1);
  do_tile<1>(xu, D11B, lam, bv, wb, d11diag, whiF, lane, col, quad, r0w, pre1, pre0);
  do_tile<2>(xu, D11B, lam, bv, wb, d11diag, whiF, lane, col, quad, r0w, pre0, pre1);
  do_tile<3>(xu, D11B, lam, bv, wb, d11diag, whiF, lane, col, quad, r0w, pre1, pre0);
  do_tile<4>(xu, D11B, lam, bv, wb, d11diag, whiF, lane, col, quad, r0w, pre0, pre1);
  do_tile<5>(xu, D11B, lam, bv, wb, d11diag, whiF, lane, col, quad, r0w, pre1, pre0);
  do_tile<6>(xu, D11B, lam, bv, wb, d11diag, whiF, lane, col, quad, r0w, pre0, pre1);
  do_tile<7>(xu, D11B, lam, bv, wb, d11diag, whiF, lane, col, quad, r0w, pre1, pre0);
  do_tile<8>(xu, D11B, lam, bv, wb, d11diag, whiF, lane, col, quad, r0w, pre0, pre1);
  do_tile<9>(xu, D11B, lam, bv, wb, d11diag, whiF, lane, col, quad, r0w, pre1, pre0);
  do_tile<10>(xu, D11B, lam, bv, wb, d11diag, whiF, lane, col, quad, r0w, pre0, pre1);
  do_tile<11>(xu, D11B, lam, bv, wb, d11diag, whiF, lane, col, quad, r0w, pre1, pre0);
  do_tile<12>(xu, D11B, lam, bv, wb, d11diag, whiF, lane, col, quad, r0w, pre0, pre1);
  do_tile<13>(xu, D11B, lam, bv, wb, d11diag, whiF, lane, col, quad, r0w, pre1, pre0);
  do_tile<14>(xu, D11B, lam, bv, wb, d11diag, whiF, lane, col, quad, r0w, pre0, pre1);
  do_tile<15>(xu, D11B, lam, bv, wb, d11diag, whiF, lane, col, quad, r0w, pre1, pre0);
  #pragma unroll
  for (int it = 0; it < 8; ++it) {
    int f = it * 64 + lane;
    int m = f >> 5, k8 = f & 31;
    uint4 v = *(const uint4*)(wb + m * WSTRIDE + k8 * 8);
    *(uint4*)(P + (size_t)(r0w + m) * KP + NXq + k8 * 8) = v;
  }
}

extern "C" void kernel_launch(void* const* d_in, const int* in_sizes, int n_in,
                              void* d_out, int out_size, void* d_ws, size_t ws_size,
                              hipStream_t stream) {
  const float* x   = (const float*)d_in[0];
  const float* u   = (const float*)d_in[1];
  const float* F   = (const float*)d_in[2];
  const float* B1  = (const float*)d_in[3];
  const float* B2  = (const float*)d_in[4];
  const float* C1  = (const float*)d_in[5];
  const float* C2  = (const float*)d_in[6];
  const float* D11 = (const float*)d_in[7];
  const float* D12 = (const float*)d_in[8];
  const float* D21 = (const float*)d_in[9];
  const float* E   = (const float*)d_in[10];
  const float* lam = (const float*)d_in[11];
  const float* bv  = (const float*)d_in[12];

  char* ws = (char*)d_ws;
  ushort* P    = (ushort*)ws;                                     // 32 MB
  float* xu    = (float*)(ws + (size_t)(32u << 20));              // 16 MB
  float* AUG0  = (float*)(ws + (size_t)(48u << 20));              // 3 MB
  float* AUG1  = (float*)(ws + (size_t)(52u << 20));              // 3 MB
  ushort* Wfull = (ushort*)(ws + (size_t)(56u << 20));            // 1.25 MB bf16
  ushort* Wxu   = (ushort*)(ws + (size_t)(58u << 20));            // 0.5 MB bf16
  ushort* D11B  = (ushort*)(ws + (size_t)(59u << 20));            // 128 KB bf16
  float* out   = (float*)d_out;
  float* AUGbuf[2] = { AUG0, AUG1 };

  k_prep<<<17152, 256, 0, stream>>>(x, u, E, F, B1, B2, C1, C2, D11, D12, D21,
                                    P, AUG0, Wxu, D11B, Wfull);
  for (int s = 0; s < 8; ++s)
    k_gj<<<dim3(8, 23 - s), 256, 0, stream>>>(AUGbuf[s & 1], AUGbuf[(s + 1) & 1],
                                              Wfull, s, s == 7);
  k_gemm<false><<<dim3(128, 2), 256, 0, stream>>>(P, Wxu, xu);    // xu = x@C1^T + u@D12^T
  k_solve<<<256, 256, 0, stream>>>(xu, D11, D11B, lam, bv, P);    // w -> P[:,512:768]
  k_gemm<true><<<dim3(128, 5), 256, 0, stream>>>(P, Wfull, out);  // dx, y
}